// Round 5
// baseline (752.111 us; speedup 1.0000x reference)
//
#include <hip/hip_runtime.h>
#include <math.h>

#define BATCH 8
#define CH    256
#define NPIX  4096
#define CKDIM 64

typedef __attribute__((ext_vector_type(8))) short short8;   // 8 bf16 (4 VGPRs)
typedef __attribute__((ext_vector_type(4))) float f32x4;    // MFMA accumulator

#define MFMA16x16(a, b, c) __builtin_amdgcn_mfma_f32_16x16x32_bf16((a), (b), (c), 0, 0, 0)

__device__ __forceinline__ unsigned short f2bf(float f) {
    union { float f; unsigned int u; } v; v.f = f;
    unsigned int u = v.u;
    u += 0x7fffu + ((u >> 16) & 1u);      // round-to-nearest-even
    return (unsigned short)(u >> 16);
}

// ---------------------------------------------------------------------------
// Kernel P: build W_all[384][256] bf16 (rows: 0-63 wq, 64-127 wk, 128-383 wg@wv)
// and bias_all[384] fp32. grid 384 x 256 threads.
// ---------------------------------------------------------------------------
__global__ void prep_kernel(const float* __restrict__ wq, const float* __restrict__ bq,
                            const float* __restrict__ wk, const float* __restrict__ bk,
                            const float* __restrict__ wv, const float* __restrict__ bv,
                            const float* __restrict__ wg,
                            unsigned short* __restrict__ W_all, float* __restrict__ bias_all) {
    int o = blockIdx.x;
    int c = threadIdx.x;
    if (o < 64) {
        W_all[o * CH + c] = f2bf(wq[o * CH + c]);
        if (c == 0) bias_all[o] = bq[o];
    } else if (o < 128) {
        int oo = o - 64;
        W_all[o * CH + c] = f2bf(wk[oo * CH + c]);
        if (c == 0) bias_all[o] = bk[oo];
    } else {
        __shared__ float wgr[CH];
        int oo = o - 128;
        wgr[c] = wg[oo * CH + c];
        __syncthreads();
        float a0 = 0.f, a1 = 0.f, a2 = 0.f, a3 = 0.f;
#pragma unroll 4
        for (int m = 0; m < CH; m += 4) {
            a0 += wgr[m + 0] * wv[(m + 0) * CH + c];
            a1 += wgr[m + 1] * wv[(m + 1) * CH + c];
            a2 += wgr[m + 2] * wv[(m + 2) * CH + c];
            a3 += wgr[m + 3] * wv[(m + 3) * CH + c];
        }
        W_all[o * CH + c] = f2bf((a0 + a1) + (a2 + a3));
        if (c == 0) {
            float b = 0.f;
            for (int m = 0; m < CH; ++m) b += wgr[m] * bv[m];
            bias_all[o] = b;
        }
    }
}

// ---------------------------------------------------------------------------
// Kernel T: transpose+convert x[b][c][n] fp32 -> xt[b][n][c] bf16.
// 64x64 tiles, 256 threads. LDS stride 65 (<=2-way banks). grid (64, 4, 8).
// ---------------------------------------------------------------------------
__global__ void xpose_kernel(const float* __restrict__ x, unsigned short* __restrict__ xt) {
    __shared__ float Tl[64][65];   // [n][c]
    int n0 = blockIdx.x * 64;
    int c0 = blockIdx.y * 64;
    int b  = blockIdx.z;
    int tid = threadIdx.x;

#pragma unroll
    for (int r = 0; r < 4; ++r) {
        int f  = r * 256 + tid;
        int c  = f >> 4;
        int n4 = f & 15;
        float4 v = *(const float4*)(x + ((size_t)b * CH + c0 + c) * NPIX + n0 + n4 * 4);
        Tl[n4 * 4 + 0][c] = v.x;
        Tl[n4 * 4 + 1][c] = v.y;
        Tl[n4 * 4 + 2][c] = v.z;
        Tl[n4 * 4 + 3][c] = v.w;
    }
    __syncthreads();
#pragma unroll
    for (int r = 0; r < 2; ++r) {
        int f    = r * 256 + tid;
        int nrow = f >> 3;
        int c8   = f & 7;
        unsigned int pk[4];
#pragma unroll
        for (int p = 0; p < 4; ++p) {
            unsigned int lo = f2bf(Tl[nrow][c8 * 8 + p * 2 + 0]);
            unsigned int hi = f2bf(Tl[nrow][c8 * 8 + p * 2 + 1]);
            pk[p] = lo | (hi << 16);
        }
        *(uint4*)(xt + ((size_t)b * NPIX + n0 + nrow) * CH + c0 + c8 * 8) = *(uint4*)pk;
    }
}

// ---------------------------------------------------------------------------
// Kernel G: qkv GEMM, og-split over blockIdx.z (3 o-groups each) -> grid
// (64, 8, 2) = 1024 blocks = 4/CU (was 2/CU grid-limited). Staging duplicated
// per z (L2-hot). y[o][n] = sum_c W_all[o][c] xt[n][c] + bias.
// ---------------------------------------------------------------------------
__global__ __launch_bounds__(256, 4)
void qkv_mfma(const unsigned short* __restrict__ xt,
              const unsigned short* __restrict__ W_all,
              const float* __restrict__ bias_all,
              unsigned short* __restrict__ qk, unsigned short* __restrict__ vp) {
    __shared__ __align__(16) unsigned short Xl[64][264];   // 33 KB, stride 264 (~conflict-min)

    int n0   = blockIdx.x * 64;
    int b    = blockIdx.y;
    int zg   = blockIdx.z;               // 0: og 0-2, 1: og 3-5
    int tid  = threadIdx.x;
    int lane = tid & 63;
    int w    = tid >> 6;
    int col  = lane & 15;
    int quad = lane >> 4;

    // stage xt tile: 64 rows x 256 ch (8 uint4/thread, coalesced)
#pragma unroll
    for (int r = 0; r < 8; ++r) {
        int f   = r * 256 + tid;
        int row = f >> 5;            // 32 uint4 per row
        int c8  = f & 31;
        *(uint4*)&Xl[row][c8 * 8] = *(const uint4*)(xt + ((size_t)b * NPIX + n0 + row) * CH + c8 * 8);
    }
    __syncthreads();

#pragma unroll
    for (int ogl = 0; ogl < 3; ++ogl) {
        int og = zg * 3 + ogl;
        int o0 = og * 64;
        const unsigned short* Arow = W_all + (size_t)(o0 + w * 16 + col) * CH + quad * 8;

        f32x4 acc[4];
#pragma unroll
        for (int t = 0; t < 4; ++t) acc[t] = (f32x4){0.f, 0.f, 0.f, 0.f};

#pragma unroll
        for (int kc = 0; kc < 8; ++kc) {
            short8 a = *(const short8*)(Arow + kc * 32);   // L2-hot (196 KB total W)
#pragma unroll
            for (int nt = 0; nt < 4; ++nt) {
                short8 bb = *(const short8*)&Xl[nt * 16 + col][kc * 32 + quad * 8];
                acc[nt] = MFMA16x16(a, bb, acc[nt]);
            }
        }

        float4 bias = *(const float4*)(bias_all + o0 + w * 16 + quad * 4);
        float bs[4] = {bias.x, bias.y, bias.z, bias.w};

        if (og < 2) {
            // q/k: transposed store qk[b][n][o] (uint2 per tile)
#pragma unroll
            for (int nt = 0; nt < 4; ++nt) {
                int n = n0 + nt * 16 + col;
                unsigned int pk[2];
#pragma unroll
                for (int p = 0; p < 2; ++p) {
                    unsigned int lo = f2bf(acc[nt][p * 2 + 0] + bs[p * 2 + 0]);
                    unsigned int hi = f2bf(acc[nt][p * 2 + 1] + bs[p * 2 + 1]);
                    pk[p] = lo | (hi << 16);
                }
                *(uint2*)(qk + ((size_t)b * NPIX + n) * 128 + o0 + w * 16 + quad * 4) = *(uint2*)pk;
            }
        } else {
#pragma unroll
            for (int nt = 0; nt < 4; ++nt) {
                int n = n0 + nt * 16 + col;
#pragma unroll
                for (int r = 0; r < 4; ++r) {
                    int oo = o0 - 128 + w * 16 + quad * 4 + r;
                    vp[((size_t)b * CH + oo) * NPIX + n] = f2bf(acc[nt][r] + bs[r]);
                }
            }
        }
    }
}

// ---------------------------------------------------------------------------
// Kernel A v9: v6 pipeline verbatim, j-tile 32 @ 512 threads -> grid 1024:
// 4 blocks/CU, 32 waves/CU (2x occupancy), 4 barrier domains. Per-wave work
// halves (A: 1 ti x 1 tj = 2 MFMA; B: acc[2][2] = 8 MFMA); per-CU totals
// unchanged. Depth-1 Q/V register prefetch (consume NEXT iter) kept exactly --
// v7/v8 proved same-iter V loads serialize (~500cyc L2 stall/iter).
// LDS 13.8 KB; VGPR ~52 (<=64 for 8 waves/SIMD).
// ---------------------------------------------------------------------------
#define LPK 72
__global__ __launch_bounds__(512, 8)
void attn_v9(const unsigned short* __restrict__ qk,   // [B][N][128]: q=0..63, k=64..127
             const unsigned short* __restrict__ vp,   // [B][256][N]
             const float* __restrict__ bg, float* __restrict__ out) {
    __shared__ __align__(16) unsigned short Qt[64][LPK];   // [i][ch]  9.2 KB
    __shared__ __align__(16) unsigned short St[32][LPK];   // [j][i]   4.6 KB

    int lin  = blockIdx.x;
    int b    = lin & 7;                 // XCD-swizzle: one batch per XCD
    int j0   = (lin >> 3) * 32;
    int tid  = threadIdx.x;
    int lane = tid & 63;
    int w    = tid >> 6;                // 0..7
    int col  = lane & 15;
    int quad = lane >> 4;

    int tjA = w & 1;              // phase-A j-subtile (0..1)
    int tiA = w >> 1;             // phase-A i-subtile (0..3)

    // iteration-invariant K fragments (global, once; B-operand: n=j, k=ch)
    short8 bK[2];
#pragma unroll
    for (int ks = 0; ks < 2; ++ks)
        bK[ks] = *(const short8*)(qk + ((size_t)b * NPIX + j0 + tjA * 16 + col) * 128 + 64 + ks * 32 + quad * 8);

    f32x4 acc[2][2];   // [o-tile][j-tile]; D: col=o, rows=j
#pragma unroll
    for (int ot = 0; ot < 2; ++ot)
#pragma unroll
        for (int tj = 0; tj < 2; ++tj) acc[ot][tj] = (f32x4){0.f, 0.f, 0.f, 0.f};

    // Q staging coords: 1 uint4/thread (64 rows x 8 chunks), coalesced
    int qrow = tid >> 3, q8 = tid & 7;
    const unsigned short* Qsrc = qk + ((size_t)b * NPIX + qrow) * 128 + q8 * 8;
    const unsigned short* Vs[2];
#pragma unroll
    for (int ot = 0; ot < 2; ++ot)
        Vs[ot] = vp + ((size_t)b * CH + (w * 2 + ot) * 16 + col) * NPIX + quad * 8;

    // prologue: prefetch i-tile 0 into regs
    uint4 qr = *(const uint4*)Qsrc;
    short8 vb[2][2];
#pragma unroll
    for (int ot = 0; ot < 2; ++ot)
#pragma unroll
        for (int ks = 0; ks < 2; ++ks)
            vb[ot][ks] = *(const short8*)(Vs[ot] + ks * 32);

    const float invN = 1.f / (float)NPIX;

    for (int i0 = 0; i0 < NPIX; i0 += 64) {
        // stage Qt from prefetched regs (safe: everyone passed prev bar2)
        *(uint4*)&Qt[qrow][q8 * 8] = qr;

        // prefetch NEXT i-tile into regs (wraps to 0 on last iter -- harmless)
        int inext = (i0 + 64) & (NPIX - 1);
        uint4 qr_n = *(const uint4*)(Qsrc + (size_t)inext * 128);
        short8 vb_n[2][2];
#pragma unroll
        for (int ot = 0; ot < 2; ++ot)
#pragma unroll
            for (int ks = 0; ks < 2; ++ks)
                vb_n[ot][ks] = *(const short8*)(Vs[ot] + inext + ks * 32);

        __syncthreads();   // bar1: Qt visible; prev phase-B St reads complete

        // ---- phase A: S[64i x 32j] = Q.K^T, elu/N -> St[j][i] bf16 ----
        {
            short8 a0 = *(const short8*)&Qt[tiA * 16 + col][quad * 8];
            short8 a1 = *(const short8*)&Qt[tiA * 16 + col][32 + quad * 8];
            f32x4 s = (f32x4){0.f, 0.f, 0.f, 0.f};
            s = MFMA16x16(a0, bK[0], s);
            s = MFMA16x16(a1, bK[1], s);
            unsigned int pk2[2];
#pragma unroll
            for (int pp = 0; pp < 2; ++pp) {
                float e0 = s[pp * 2 + 0];
                float e1 = s[pp * 2 + 1];
                float g0 = __expf(e0) - 1.f;
                float g1 = __expf(e1) - 1.f;
                e0 = (e0 > 0.f) ? e0 : g0;
                e1 = (e1 > 0.f) ? e1 : g1;
                e0 *= invN;
                e1 *= invN;
                unsigned int rpk;
                asm("v_cvt_pk_bf16_f32 %0, %1, %2" : "=v"(rpk) : "v"(e0), "v"(e1));
                pk2[pp] = rpk;
            }
            // D of phase A: col=j, rows=4 consecutive i -> St[j][i] uint2
            *(uint2*)&St[tjA * 16 + col][tiA * 16 + quad * 4] = *(uint2*)pk2;
        }
        __syncthreads();   // bar2: St ready for all waves

        // ---- phase B: acc[ot][tj] += S(A: m=j,k=i) x V(B-regs: n=o,k=i) ----
#pragma unroll
        for (int ks = 0; ks < 2; ++ks) {
            short8 sb[2];
#pragma unroll
            for (int tj = 0; tj < 2; ++tj)
                sb[tj] = *(const short8*)&St[tj * 16 + col][ks * 32 + quad * 8];
            __builtin_amdgcn_s_setprio(1);
#pragma unroll
            for (int ot = 0; ot < 2; ++ot)
#pragma unroll
                for (int tj = 0; tj < 2; ++tj)
                    acc[ot][tj] = MFMA16x16(sb[tj], vb[ot][ks], acc[ot][tj]);
            __builtin_amdgcn_s_setprio(0);
        }

        // rotate prefetch regs
        qr = qr_n;
#pragma unroll
        for (int ot = 0; ot < 2; ++ot)
#pragma unroll
            for (int ks = 0; ks < 2; ++ks)
                vb[ot][ks] = vb_n[ot][ks];
    }

    // epilogue: D col=o, rows=4 consecutive j -> float4 stores
#pragma unroll
    for (int ot = 0; ot < 2; ++ot) {
        int o = (w * 2 + ot) * 16 + col;
        float bgv = bg[o];
#pragma unroll
        for (int tj = 0; tj < 2; ++tj) {
            int j = j0 + tj * 16 + quad * 4;
            float4 st;
            st.x = acc[ot][tj][0] + bgv;
            st.y = acc[ot][tj][1] + bgv;
            st.z = acc[ot][tj][2] + bgv;
            st.w = acc[ot][tj][3] + bgv;
            *(float4*)&out[((size_t)b * CH + o) * NPIX + j] = st;
        }
    }
}

// ---------------------------------------------------------------------------
extern "C" void kernel_launch(void* const* d_in, const int* in_sizes, int n_in,
                              void* d_out, int out_size, void* d_ws, size_t ws_size,
                              hipStream_t stream) {
    const float* x  = (const float*)d_in[0];
    const float* wq = (const float*)d_in[1];
    const float* bq = (const float*)d_in[2];
    const float* wk = (const float*)d_in[3];
    const float* bk = (const float*)d_in[4];
    const float* wv = (const float*)d_in[5];
    const float* bv = (const float*)d_in[6];
    const float* wg = (const float*)d_in[7];
    const float* bg = (const float*)d_in[8];
    float* out = (float*)d_out;

    unsigned short* W_all = (unsigned short*)d_ws;
    float* bias_all = (float*)(W_all + 384 * 256);
    unsigned short* xt = (unsigned short*)(bias_all + 384);
    unsigned short* qk = xt + (size_t)BATCH * NPIX * CH;
    unsigned short* vp = qk + (size_t)BATCH * NPIX * 128;

    prep_kernel<<<dim3(384), dim3(256), 0, stream>>>(wq, bq, wk, bk, wv, bv, wg, W_all, bias_all);
    xpose_kernel<<<dim3(NPIX / 64, CH / 64, BATCH), dim3(256), 0, stream>>>(x, xt);
    qkv_mfma<<<dim3(NPIX / 64, BATCH, 2), dim3(256), 0, stream>>>(xt, W_all, bias_all, qk, vp);
    attn_v9<<<dim3(NPIX / 32 * BATCH), dim3(512), 0, stream>>>(qk, vp, bg, out);
}

// Round 6
// 257.501 us; speedup vs baseline: 2.9208x; 2.9208x over previous
//
#include <hip/hip_runtime.h>
#include <math.h>

#define BATCH 8
#define CH    256
#define NPIX  4096
#define CKDIM 64

typedef __attribute__((ext_vector_type(8))) short short8;   // 8 bf16 (4 VGPRs)
typedef __attribute__((ext_vector_type(4))) float f32x4;    // MFMA accumulator

#define MFMA16x16(a, b, c) __builtin_amdgcn_mfma_f32_16x16x32_bf16((a), (b), (c), 0, 0, 0)

__device__ __forceinline__ unsigned short f2bf(float f) {
    union { float f; unsigned int u; } v; v.f = f;
    unsigned int u = v.u;
    u += 0x7fffu + ((u >> 16) & 1u);      // round-to-nearest-even
    return (unsigned short)(u >> 16);
}

// ---------------------------------------------------------------------------
// Kernel P: build W_all[384][256] bf16 (rows: 0-63 wq, 64-127 wk, 128-383 wg@wv)
// and bias_all[384] fp32. grid 384 x 256 threads. wg row staged in LDS;
// m-loop unrolled x4 with independent accumulators.
// ---------------------------------------------------------------------------
__global__ void prep_kernel(const float* __restrict__ wq, const float* __restrict__ bq,
                            const float* __restrict__ wk, const float* __restrict__ bk,
                            const float* __restrict__ wv, const float* __restrict__ bv,
                            const float* __restrict__ wg,
                            unsigned short* __restrict__ W_all, float* __restrict__ bias_all) {
    int o = blockIdx.x;
    int c = threadIdx.x;
    if (o < 64) {
        W_all[o * CH + c] = f2bf(wq[o * CH + c]);
        if (c == 0) bias_all[o] = bq[o];
    } else if (o < 128) {
        int oo = o - 64;
        W_all[o * CH + c] = f2bf(wk[oo * CH + c]);
        if (c == 0) bias_all[o] = bk[oo];
    } else {
        __shared__ float wgr[CH];
        int oo = o - 128;
        wgr[c] = wg[oo * CH + c];
        __syncthreads();
        float a0 = 0.f, a1 = 0.f, a2 = 0.f, a3 = 0.f;
#pragma unroll 4
        for (int m = 0; m < CH; m += 4) {
            a0 += wgr[m + 0] * wv[(m + 0) * CH + c];
            a1 += wgr[m + 1] * wv[(m + 1) * CH + c];
            a2 += wgr[m + 2] * wv[(m + 2) * CH + c];
            a3 += wgr[m + 3] * wv[(m + 3) * CH + c];
        }
        W_all[o * CH + c] = f2bf((a0 + a1) + (a2 + a3));
        if (c == 0) {
            float b = 0.f;
            for (int m = 0; m < CH; ++m) b += wgr[m] * bv[m];
            bias_all[o] = b;
        }
    }
}

// ---------------------------------------------------------------------------
// Kernel G': FUSED xpose+qkv. Reads x[b][c][n] fp32 directly; transposes+
// converts to Xl[n][c] bf16 in LDS (4 passes of 64 channels through Tl, the
// proven xpose pattern, now LDS->LDS); then the unchanged 6-og MFMA loop.
// Eliminates the xt intermediate (34 MB traffic) and one kernel launch.
// grid (64, 8), 256 threads. LDS 50.4 KB.
// ---------------------------------------------------------------------------
__global__ __launch_bounds__(256, 2)
void qkvf_mfma(const float* __restrict__ x,
               const unsigned short* __restrict__ W_all,
               const float* __restrict__ bias_all,
               unsigned short* __restrict__ qk, unsigned short* __restrict__ vp) {
    __shared__ float Tl[64][65];                           // 16.6 KB transpose tile
    __shared__ __align__(16) unsigned short Xl[64][264];   // 33.8 KB, stride 264

    int n0   = blockIdx.x * 64;
    int b    = blockIdx.y;
    int tid  = threadIdx.x;
    int lane = tid & 63;
    int w    = tid >> 6;
    int col  = lane & 15;
    int quad = lane >> 4;

    // stage: x[b][c0+c][n0..n0+63] fp32 -> Xl[n][c0+c] bf16, 4 passes of 64 ch
    for (int c0 = 0; c0 < CH; c0 += 64) {
        if (c0) __syncthreads();           // prev pack readers done before Tl reuse
#pragma unroll
        for (int r = 0; r < 4; ++r) {
            int f  = r * 256 + tid;
            int c  = f >> 4;
            int n4 = f & 15;
            float4 v = *(const float4*)(x + ((size_t)b * CH + c0 + c) * NPIX + n0 + n4 * 4);
            Tl[n4 * 4 + 0][c] = v.x;
            Tl[n4 * 4 + 1][c] = v.y;
            Tl[n4 * 4 + 2][c] = v.z;
            Tl[n4 * 4 + 3][c] = v.w;
        }
        __syncthreads();
#pragma unroll
        for (int r = 0; r < 2; ++r) {
            int f    = r * 256 + tid;
            int nrow = f >> 3;
            int c8   = f & 7;
            unsigned int pk[4];
#pragma unroll
            for (int p = 0; p < 4; ++p) {
                unsigned int lo = f2bf(Tl[nrow][c8 * 8 + p * 2 + 0]);
                unsigned int hi = f2bf(Tl[nrow][c8 * 8 + p * 2 + 1]);
                pk[p] = lo | (hi << 16);
            }
            *(uint4*)&Xl[nrow][c0 + c8 * 8] = *(uint4*)pk;
        }
    }
    __syncthreads();

#pragma unroll
    for (int og = 0; og < 6; ++og) {
        int o0 = og * 64;
        const unsigned short* Arow = W_all + (size_t)(o0 + w * 16 + col) * CH + quad * 8;

        f32x4 acc[4];
#pragma unroll
        for (int t = 0; t < 4; ++t) acc[t] = (f32x4){0.f, 0.f, 0.f, 0.f};

#pragma unroll
        for (int kc = 0; kc < 8; ++kc) {
            short8 a = *(const short8*)(Arow + kc * 32);   // L2-hot (196 KB total W)
#pragma unroll
            for (int nt = 0; nt < 4; ++nt) {
                short8 bb = *(const short8*)&Xl[nt * 16 + col][kc * 32 + quad * 8];
                acc[nt] = MFMA16x16(a, bb, acc[nt]);
            }
        }

        float4 bias = *(const float4*)(bias_all + o0 + w * 16 + quad * 4);
        float bs[4] = {bias.x, bias.y, bias.z, bias.w};

        if (og < 2) {
            // q/k: transposed store qk[b][n][o] (uint2 per tile)
#pragma unroll
            for (int nt = 0; nt < 4; ++nt) {
                int n = n0 + nt * 16 + col;
                unsigned int pk[2];
#pragma unroll
                for (int p = 0; p < 2; ++p) {
                    unsigned int lo = f2bf(acc[nt][p * 2 + 0] + bs[p * 2 + 0]);
                    unsigned int hi = f2bf(acc[nt][p * 2 + 1] + bs[p * 2 + 1]);
                    pk[p] = lo | (hi << 16);
                }
                *(uint2*)(qk + ((size_t)b * NPIX + n) * 128 + o0 + w * 16 + quad * 4) = *(uint2*)pk;
            }
        } else {
#pragma unroll
            for (int nt = 0; nt < 4; ++nt) {
                int n = n0 + nt * 16 + col;
#pragma unroll
                for (int r = 0; r < 4; ++r) {
                    int oo = o0 - 128 + w * 16 + quad * 4 + r;
                    vp[((size_t)b * CH + oo) * NPIX + n] = f2bf(acc[nt][r] + bs[r]);
                }
            }
        }
    }
}

// ---------------------------------------------------------------------------
// Kernel A v6 (VERBATIM revert -- measured 153.7 us, VGPR 56, twice-confirmed).
// j-tile 64, 8 waves, 2 blocks/CU. V direct from L2 with depth-1 register
// prefetch; Q coalesced-staged with depth-1 prefetch; 2 barriers/iter;
// XCD swizzle (one batch per XCD). LDS 18.4 KB.
// ---------------------------------------------------------------------------
#define LPK 72
__global__ __launch_bounds__(512, 4)
void attn_v6(const unsigned short* __restrict__ qk,   // [B][N][128]: q=0..63, k=64..127
             const unsigned short* __restrict__ vp,   // [B][256][N]
             const float* __restrict__ bg, float* __restrict__ out) {
    __shared__ __align__(16) unsigned short Qt[64][LPK];   // [i][ch]  9.2 KB
    __shared__ __align__(16) unsigned short St[64][LPK];   // [j][i]   9.2 KB

    int lin  = blockIdx.y * gridDim.x + blockIdx.x;
    int b    = lin & 7;                 // XCD-swizzle: one batch per XCD
    int j0   = (lin >> 3) * 64;
    int tid  = threadIdx.x;
    int lane = tid & 63;
    int w    = tid >> 6;
    int col  = lane & 15;
    int quad = lane >> 4;

    int tjA = w & 3;              // phase-A j-tile (this wave's K column block)
    int tiP = (w >> 2) * 2;       // phase-A i-tile pair

    // iteration-invariant K fragments (global, once; B-operand: n=j, k=ch)
    short8 bK[2];
#pragma unroll
    for (int ks = 0; ks < 2; ++ks)
        bK[ks] = *(const short8*)(qk + ((size_t)b * NPIX + j0 + tjA * 16 + col) * 128 + 64 + ks * 32 + quad * 8);

    f32x4 acc[2][4];   // [o-tile][j-tile]; D: col=o, rows=j
#pragma unroll
    for (int ot = 0; ot < 2; ++ot)
#pragma unroll
        for (int tj = 0; tj < 4; ++tj) acc[ot][tj] = (f32x4){0.f, 0.f, 0.f, 0.f};

    // per-thread staging coords
    int qrow = tid >> 3, q8 = tid & 7;
    const unsigned short* Qsrc = qk + ((size_t)b * NPIX + qrow) * 128 + q8 * 8;
    const unsigned short* Vsrc[2];
#pragma unroll
    for (int ot = 0; ot < 2; ++ot)
        Vsrc[ot] = vp + ((size_t)b * CH + (w * 2 + ot) * 16 + col) * NPIX + quad * 8;

    // prologue: prefetch i-tile 0 into regs
    uint4 qr = *(const uint4*)Qsrc;
    short8 vb[2][2];
#pragma unroll
    for (int ot = 0; ot < 2; ++ot)
#pragma unroll
        for (int ks = 0; ks < 2; ++ks)
            vb[ot][ks] = *(const short8*)(Vsrc[ot] + ks * 32);

    const float invN = 1.f / (float)NPIX;

    for (int i0 = 0; i0 < NPIX; i0 += 64) {
        // stage Qt from prefetched regs (safe: everyone passed prev bar2)
        *(uint4*)&Qt[qrow][q8 * 8] = qr;

        // prefetch NEXT i-tile into regs (wraps to 0 on last iter -- harmless)
        int inext = (i0 + 64) & (NPIX - 1);
        uint4 qr_n = *(const uint4*)(Qsrc + (size_t)inext * 128);
        short8 vb_n[2][2];
#pragma unroll
        for (int ot = 0; ot < 2; ++ot)
#pragma unroll
            for (int ks = 0; ks < 2; ++ks)
                vb_n[ot][ks] = *(const short8*)(Vsrc[ot] + inext + ks * 32);

        __syncthreads();   // bar1: Qt visible; prev phase-B St reads complete

        // ---- phase A: S[64x64] = Q.K^T, elu/N -> St[j][i] bf16 ----
#pragma unroll
        for (int t = 0; t < 2; ++t) {
            int ti = tiP + t;
            short8 a0 = *(const short8*)&Qt[ti * 16 + col][quad * 8];
            short8 a1 = *(const short8*)&Qt[ti * 16 + col][32 + quad * 8];
            f32x4 s = (f32x4){0.f, 0.f, 0.f, 0.f};
            s = MFMA16x16(a0, bK[0], s);
            s = MFMA16x16(a1, bK[1], s);
            unsigned int pk2[2];
#pragma unroll
            for (int pp = 0; pp < 2; ++pp) {
                float e0 = s[pp * 2 + 0];
                float e1 = s[pp * 2 + 1];
                float g0 = __expf(e0) - 1.f;
                float g1 = __expf(e1) - 1.f;
                e0 = (e0 > 0.f) ? e0 : g0;
                e1 = (e1 > 0.f) ? e1 : g1;
                e0 *= invN;
                e1 *= invN;
                unsigned int rpk;
                asm("v_cvt_pk_bf16_f32 %0, %1, %2" : "=v"(rpk) : "v"(e0), "v"(e1));
                pk2[pp] = rpk;
            }
            // D of phase A: col=j, rows=4 consecutive i -> St[j][i] uint2
            *(uint2*)&St[tjA * 16 + col][ti * 16 + quad * 4] = *(uint2*)pk2;
        }
        __syncthreads();   // bar2: St ready for all waves

        // ---- phase B: acc[ot][tj] += S(A: m=j,k=i) x V(B-regs: n=o,k=i) ----
#pragma unroll
        for (int ks = 0; ks < 2; ++ks) {
            short8 sb[4];
#pragma unroll
            for (int tj = 0; tj < 4; ++tj)
                sb[tj] = *(const short8*)&St[tj * 16 + col][ks * 32 + quad * 8];
            __builtin_amdgcn_s_setprio(1);
#pragma unroll
            for (int ot = 0; ot < 2; ++ot)
#pragma unroll
                for (int tj = 0; tj < 4; ++tj)
                    acc[ot][tj] = MFMA16x16(sb[tj], vb[ot][ks], acc[ot][tj]);
            __builtin_amdgcn_s_setprio(0);
        }

        // rotate prefetch regs
        qr = qr_n;
#pragma unroll
        for (int ot = 0; ot < 2; ++ot)
#pragma unroll
            for (int ks = 0; ks < 2; ++ks)
                vb[ot][ks] = vb_n[ot][ks];
    }

    // epilogue: D col=o, rows=4 consecutive j -> float4 stores
#pragma unroll
    for (int ot = 0; ot < 2; ++ot) {
        int o = (w * 2 + ot) * 16 + col;
        float bgv = bg[o];
#pragma unroll
        for (int tj = 0; tj < 4; ++tj) {
            int j = j0 + tj * 16 + quad * 4;
            float4 st;
            st.x = acc[ot][tj][0] + bgv;
            st.y = acc[ot][tj][1] + bgv;
            st.z = acc[ot][tj][2] + bgv;
            st.w = acc[ot][tj][3] + bgv;
            *(float4*)&out[((size_t)b * CH + o) * NPIX + j] = st;
        }
    }
}

// ---------------------------------------------------------------------------
extern "C" void kernel_launch(void* const* d_in, const int* in_sizes, int n_in,
                              void* d_out, int out_size, void* d_ws, size_t ws_size,
                              hipStream_t stream) {
    const float* x  = (const float*)d_in[0];
    const float* wq = (const float*)d_in[1];
    const float* bq = (const float*)d_in[2];
    const float* wk = (const float*)d_in[3];
    const float* bk = (const float*)d_in[4];
    const float* wv = (const float*)d_in[5];
    const float* bv = (const float*)d_in[6];
    const float* wg = (const float*)d_in[7];
    const float* bg = (const float*)d_in[8];
    float* out = (float*)d_out;

    unsigned short* W_all = (unsigned short*)d_ws;
    float* bias_all = (float*)(W_all + 384 * 256);
    unsigned short* qk = (unsigned short*)(bias_all + 384);
    unsigned short* vp = qk + (size_t)BATCH * NPIX * 128;

    prep_kernel<<<dim3(384), dim3(256), 0, stream>>>(wq, bq, wk, bk, wv, bv, wg, W_all, bias_all);
    qkvf_mfma<<<dim3(NPIX / 64, BATCH), dim3(256), 0, stream>>>(x, W_all, bias_all, qk, vp);
    attn_v6<<<dim3(NPIX / 64, BATCH), dim3(512), 0, stream>>>(qk, vp, bg, out);
}

// Round 7
// 256.102 us; speedup vs baseline: 2.9368x; 1.0055x over previous
//
#include <hip/hip_runtime.h>
#include <math.h>

#define BATCH 8
#define CH    256
#define NPIX  4096
#define CKDIM 64

typedef __attribute__((ext_vector_type(8))) short short8;   // 8 bf16 (4 VGPRs)
typedef __attribute__((ext_vector_type(4))) float f32x4;    // MFMA accumulator

#define MFMA16x16(a, b, c) __builtin_amdgcn_mfma_f32_16x16x32_bf16((a), (b), (c), 0, 0, 0)

__device__ __forceinline__ unsigned short f2bf(float f) {
    union { float f; unsigned int u; } v; v.f = f;
    unsigned int u = v.u;
    u += 0x7fffu + ((u >> 16) & 1u);      // round-to-nearest-even
    return (unsigned short)(u >> 16);
}

// ---------------------------------------------------------------------------
// Kernel P: build W_all[384][256] bf16 (rows: 0-63 wq, 64-127 wk, 128-383 wg@wv)
// and bias_all[384] fp32. grid 384 x 256 threads. wg row staged in LDS;
// m-loop unrolled x4 with independent accumulators.
// ---------------------------------------------------------------------------
__global__ void prep_kernel(const float* __restrict__ wq, const float* __restrict__ bq,
                            const float* __restrict__ wk, const float* __restrict__ bk,
                            const float* __restrict__ wv, const float* __restrict__ bv,
                            const float* __restrict__ wg,
                            unsigned short* __restrict__ W_all, float* __restrict__ bias_all) {
    int o = blockIdx.x;
    int c = threadIdx.x;
    if (o < 64) {
        W_all[o * CH + c] = f2bf(wq[o * CH + c]);
        if (c == 0) bias_all[o] = bq[o];
    } else if (o < 128) {
        int oo = o - 64;
        W_all[o * CH + c] = f2bf(wk[oo * CH + c]);
        if (c == 0) bias_all[o] = bk[oo];
    } else {
        __shared__ float wgr[CH];
        int oo = o - 128;
        wgr[c] = wg[oo * CH + c];
        __syncthreads();
        float a0 = 0.f, a1 = 0.f, a2 = 0.f, a3 = 0.f;
#pragma unroll 4
        for (int m = 0; m < CH; m += 4) {
            a0 += wgr[m + 0] * wv[(m + 0) * CH + c];
            a1 += wgr[m + 1] * wv[(m + 1) * CH + c];
            a2 += wgr[m + 2] * wv[(m + 2) * CH + c];
            a3 += wgr[m + 3] * wv[(m + 3) * CH + c];
        }
        W_all[o * CH + c] = f2bf((a0 + a1) + (a2 + a3));
        if (c == 0) {
            float b = 0.f;
            for (int m = 0; m < CH; ++m) b += wgr[m] * bv[m];
            bias_all[o] = b;
        }
    }
}

// ---------------------------------------------------------------------------
// Kernel G': FUSED xpose+qkv (unchanged from round 6 -- passed). Reads x
// fp32 directly, transposes+converts to Xl bf16 in LDS, then 6-og MFMA loop.
// grid (64, 8), 256 threads. LDS 50.4 KB.
// ---------------------------------------------------------------------------
__global__ __launch_bounds__(256, 2)
void qkvf_mfma(const float* __restrict__ x,
               const unsigned short* __restrict__ W_all,
               const float* __restrict__ bias_all,
               unsigned short* __restrict__ qk, unsigned short* __restrict__ vp) {
    __shared__ float Tl[64][65];                           // 16.6 KB transpose tile
    __shared__ __align__(16) unsigned short Xl[64][264];   // 33.8 KB, stride 264

    int n0   = blockIdx.x * 64;
    int b    = blockIdx.y;
    int tid  = threadIdx.x;
    int lane = tid & 63;
    int w    = tid >> 6;
    int col  = lane & 15;
    int quad = lane >> 4;

    // stage: x[b][c0+c][n0..n0+63] fp32 -> Xl[n][c0+c] bf16, 4 passes of 64 ch
    for (int c0 = 0; c0 < CH; c0 += 64) {
        if (c0) __syncthreads();           // prev pack readers done before Tl reuse
#pragma unroll
        for (int r = 0; r < 4; ++r) {
            int f  = r * 256 + tid;
            int c  = f >> 4;
            int n4 = f & 15;
            float4 v = *(const float4*)(x + ((size_t)b * CH + c0 + c) * NPIX + n0 + n4 * 4);
            Tl[n4 * 4 + 0][c] = v.x;
            Tl[n4 * 4 + 1][c] = v.y;
            Tl[n4 * 4 + 2][c] = v.z;
            Tl[n4 * 4 + 3][c] = v.w;
        }
        __syncthreads();
#pragma unroll
        for (int r = 0; r < 2; ++r) {
            int f    = r * 256 + tid;
            int nrow = f >> 3;
            int c8   = f & 7;
            unsigned int pk[4];
#pragma unroll
            for (int p = 0; p < 4; ++p) {
                unsigned int lo = f2bf(Tl[nrow][c8 * 8 + p * 2 + 0]);
                unsigned int hi = f2bf(Tl[nrow][c8 * 8 + p * 2 + 1]);
                pk[p] = lo | (hi << 16);
            }
            *(uint4*)&Xl[nrow][c0 + c8 * 8] = *(uint4*)pk;
        }
    }
    __syncthreads();

#pragma unroll
    for (int og = 0; og < 6; ++og) {
        int o0 = og * 64;
        const unsigned short* Arow = W_all + (size_t)(o0 + w * 16 + col) * CH + quad * 8;

        f32x4 acc[4];
#pragma unroll
        for (int t = 0; t < 4; ++t) acc[t] = (f32x4){0.f, 0.f, 0.f, 0.f};

#pragma unroll
        for (int kc = 0; kc < 8; ++kc) {
            short8 a = *(const short8*)(Arow + kc * 32);   // L2-hot (196 KB total W)
#pragma unroll
            for (int nt = 0; nt < 4; ++nt) {
                short8 bb = *(const short8*)&Xl[nt * 16 + col][kc * 32 + quad * 8];
                acc[nt] = MFMA16x16(a, bb, acc[nt]);
            }
        }

        float4 bias = *(const float4*)(bias_all + o0 + w * 16 + quad * 4);
        float bs[4] = {bias.x, bias.y, bias.z, bias.w};

        if (og < 2) {
            // q/k: transposed store qk[b][n][o] (uint2 per tile)
#pragma unroll
            for (int nt = 0; nt < 4; ++nt) {
                int n = n0 + nt * 16 + col;
                unsigned int pk[2];
#pragma unroll
                for (int p = 0; p < 2; ++p) {
                    unsigned int lo = f2bf(acc[nt][p * 2 + 0] + bs[p * 2 + 0]);
                    unsigned int hi = f2bf(acc[nt][p * 2 + 1] + bs[p * 2 + 1]);
                    pk[p] = lo | (hi << 16);
                }
                *(uint2*)(qk + ((size_t)b * NPIX + n) * 128 + o0 + w * 16 + quad * 4) = *(uint2*)pk;
            }
        } else {
#pragma unroll
            for (int nt = 0; nt < 4; ++nt) {
                int n = n0 + nt * 16 + col;
#pragma unroll
                for (int r = 0; r < 4; ++r) {
                    int oo = o0 - 128 + w * 16 + quad * 4 + r;
                    vp[((size_t)b * CH + oo) * NPIX + n] = f2bf(acc[nt][r] + bs[r]);
                }
            }
        }
    }
}

// ---------------------------------------------------------------------------
// Kernel A v11: v6 load patterns byte-identical; ONE barrier per iteration via
// double-buffered Qt AND St. Body(t): BAR -> stage Qt[(t+1)&1]=Q(t+1) (regs
// prefetched last body) -> issue loads Q(t+2),V(t) -> phaseB(t-1) -> phaseA(t).
// Every LDS write->read / read->write crosses exactly one barrier:
//   Qt[(t+1)&1] staged body t, read by A(t+1) after body-(t+1) BAR;
//   St[t&1] written by A(t), read by B(t) after body-(t+1) BAR;
//   WAR on both parities crosses >=1 barrier (A(t-1) read Qt[(t-1)&1] before
//   body-t BAR; B(t-2) read St[t&1] before body-(t-1) BAR... before body-t BAR).
// De-phases waves across a full-iteration window so B's MFMA overlaps A's
// VALU/LDS across waves (v6's 2-barrier structure bunched all waves into the
// same sub-phase: pipe-busy SUMMED to the wall; target is the max).
// LDS 36.9 KB; 2 blocks/CU; XCD swizzle kept.
// ---------------------------------------------------------------------------
#define LPK 72
__global__ __launch_bounds__(512, 4)
void attn_v11(const unsigned short* __restrict__ qk,   // [B][N][128]: q=0..63, k=64..127
              const unsigned short* __restrict__ vp,   // [B][256][N]
              const float* __restrict__ bg, float* __restrict__ out) {
    __shared__ __align__(16) unsigned short Qt[2][64][LPK];   // [buf][i][ch] 18.4 KB
    __shared__ __align__(16) unsigned short St[2][64][LPK];   // [buf][j][i]  18.4 KB

    int lin  = blockIdx.y * gridDim.x + blockIdx.x;
    int b    = lin & 7;                 // XCD-swizzle: one batch per XCD
    int j0   = (lin >> 3) * 64;
    int tid  = threadIdx.x;
    int lane = tid & 63;
    int w    = tid >> 6;
    int col  = lane & 15;
    int quad = lane >> 4;

    int tjA = w & 3;              // phase-A j-tile (this wave's K column block)
    int tiP = (w >> 2) * 2;       // phase-A i-tile pair

    // iteration-invariant K fragments (global, once; B-operand: n=j, k=ch)
    short8 bK[2];
#pragma unroll
    for (int ks = 0; ks < 2; ++ks)
        bK[ks] = *(const short8*)(qk + ((size_t)b * NPIX + j0 + tjA * 16 + col) * 128 + 64 + ks * 32 + quad * 8);

    f32x4 acc[2][4];   // [o-tile][j-tile]; D: col=o, rows=j
#pragma unroll
    for (int ot = 0; ot < 2; ++ot)
#pragma unroll
        for (int tj = 0; tj < 4; ++tj) acc[ot][tj] = (f32x4){0.f, 0.f, 0.f, 0.f};

    // per-thread staging coords (v6-identical coalesced patterns)
    int qrow = tid >> 3, q8 = tid & 7;
    const unsigned short* Qsrc = qk + ((size_t)b * NPIX + qrow) * 128 + q8 * 8;
    const unsigned short* Vsrc[2];
#pragma unroll
    for (int ot = 0; ot < 2; ++ot)
        Vsrc[ot] = vp + ((size_t)b * CH + (w * 2 + ot) * 16 + col) * NPIX + quad * 8;

    const float invN = 1.f / (float)NPIX;

    // ---- prologue ----
    // Qt[0] = Q(0); vb = V(0); qrA = Q(1)
    {
        uint4 q0 = *(const uint4*)Qsrc;
        *(uint4*)&Qt[0][qrow][q8 * 8] = q0;
    }
    uint4 qrA = *(const uint4*)(Qsrc + (size_t)64 * 128);   // Q(1)
    short8 vb[2][2];
#pragma unroll
    for (int ot = 0; ot < 2; ++ot)
#pragma unroll
        for (int ks = 0; ks < 2; ++ks)
            vb[ot][ks] = *(const short8*)(Vsrc[ot] + ks * 32);   // V(0)

    __syncthreads();   // Qt[0] visible

    // A(0): Qt[0] -> St[0]
#pragma unroll
    for (int t = 0; t < 2; ++t) {
        int ti = tiP + t;
        short8 a0 = *(const short8*)&Qt[0][ti * 16 + col][quad * 8];
        short8 a1 = *(const short8*)&Qt[0][ti * 16 + col][32 + quad * 8];
        f32x4 s = (f32x4){0.f, 0.f, 0.f, 0.f};
        s = MFMA16x16(a0, bK[0], s);
        s = MFMA16x16(a1, bK[1], s);
        unsigned int pk2[2];
#pragma unroll
        for (int pp = 0; pp < 2; ++pp) {
            float e0 = s[pp * 2 + 0];
            float e1 = s[pp * 2 + 1];
            float g0 = __expf(e0) - 1.f;
            float g1 = __expf(e1) - 1.f;
            e0 = (e0 > 0.f) ? e0 : g0;
            e1 = (e1 > 0.f) ? e1 : g1;
            e0 *= invN;
            e1 *= invN;
            unsigned int rpk;
            asm("v_cvt_pk_bf16_f32 %0, %1, %2" : "=v"(rpk) : "v"(e0), "v"(e1));
            pk2[pp] = rpk;
        }
        *(uint2*)&St[0][tjA * 16 + col][ti * 16 + quad * 4] = *(uint2*)pk2;
    }
    // stage Qt[1] = Q(1); prefetch Q(2)
    *(uint4*)&Qt[1][qrow][q8 * 8] = qrA;
    qrA = *(const uint4*)(Qsrc + (size_t)(2 * 64) * 128);   // Q(2)

    // ---- main loop: body it handles B(it-1) and A(it) ----
    for (int it = 1; it < NPIX / 64; ++it) {
        int pw = it & 1;            // A reads Qt[pw], writes St[pw]

        __syncthreads();            // one barrier per iteration

        // stage Qt[pw^1] = Q(it+1) (regs loaded last body)
        *(uint4*)&Qt[pw ^ 1][qrow][q8 * 8] = qrA;

        // issue prefetches: Q(it+2) [wraps harmlessly], V(it)
        {
            size_t iq = (size_t)(((it + 2) * 64) & (NPIX - 1));
            qrA = *(const uint4*)(Qsrc + iq * 128);
        }
        int iv = it * 64;
        short8 vb_n[2][2];
#pragma unroll
        for (int ot = 0; ot < 2; ++ot)
#pragma unroll
            for (int ks = 0; ks < 2; ++ks)
                vb_n[ot][ks] = *(const short8*)(Vsrc[ot] + iv + ks * 32);

        // ---- phase B(it-1): acc += S(St[pw^1]) x V(vb = V(it-1)) ----
#pragma unroll
        for (int ks = 0; ks < 2; ++ks) {
            short8 sb[4];
#pragma unroll
            for (int tj = 0; tj < 4; ++tj)
                sb[tj] = *(const short8*)&St[pw ^ 1][tj * 16 + col][ks * 32 + quad * 8];
            __builtin_amdgcn_s_setprio(1);
#pragma unroll
            for (int ot = 0; ot < 2; ++ot)
#pragma unroll
                for (int tj = 0; tj < 4; ++tj)
                    acc[ot][tj] = MFMA16x16(sb[tj], vb[ot][ks], acc[ot][tj]);
            __builtin_amdgcn_s_setprio(0);
        }

        // ---- phase A(it): Qt[pw] -> St[pw] ----
#pragma unroll
        for (int t = 0; t < 2; ++t) {
            int ti = tiP + t;
            short8 a0 = *(const short8*)&Qt[pw][ti * 16 + col][quad * 8];
            short8 a1 = *(const short8*)&Qt[pw][ti * 16 + col][32 + quad * 8];
            f32x4 s = (f32x4){0.f, 0.f, 0.f, 0.f};
            s = MFMA16x16(a0, bK[0], s);
            s = MFMA16x16(a1, bK[1], s);
            unsigned int pk2[2];
#pragma unroll
            for (int pp = 0; pp < 2; ++pp) {
                float e0 = s[pp * 2 + 0];
                float e1 = s[pp * 2 + 1];
                float g0 = __expf(e0) - 1.f;
                float g1 = __expf(e1) - 1.f;
                e0 = (e0 > 0.f) ? e0 : g0;
                e1 = (e1 > 0.f) ? e1 : g1;
                e0 *= invN;
                e1 *= invN;
                unsigned int rpk;
                asm("v_cvt_pk_bf16_f32 %0, %1, %2" : "=v"(rpk) : "v"(e0), "v"(e1));
                pk2[pp] = rpk;
            }
            *(uint2*)&St[pw][tjA * 16 + col][ti * 16 + quad * 4] = *(uint2*)pk2;
        }

        // rotate V regs (vb <- V(it))
#pragma unroll
        for (int ot = 0; ot < 2; ++ot)
#pragma unroll
            for (int ks = 0; ks < 2; ++ks)
                vb[ot][ks] = vb_n[ot][ks];
    }

    // ---- epilogue: B(63): St[1], vb = V(63) ----
    __syncthreads();
#pragma unroll
    for (int ks = 0; ks < 2; ++ks) {
        short8 sb[4];
#pragma unroll
        for (int tj = 0; tj < 4; ++tj)
            sb[tj] = *(const short8*)&St[1][tj * 16 + col][ks * 32 + quad * 8];
#pragma unroll
        for (int ot = 0; ot < 2; ++ot)
#pragma unroll
            for (int tj = 0; tj < 4; ++tj)
                acc[ot][tj] = MFMA16x16(sb[tj], vb[ot][ks], acc[ot][tj]);
    }

    // epilogue: D col=o, rows=4 consecutive j -> float4 stores
#pragma unroll
    for (int ot = 0; ot < 2; ++ot) {
        int o = (w * 2 + ot) * 16 + col;
        float bgv = bg[o];
#pragma unroll
        for (int tj = 0; tj < 4; ++tj) {
            int j = j0 + tj * 16 + quad * 4;
            float4 st;
            st.x = acc[ot][tj][0] + bgv;
            st.y = acc[ot][tj][1] + bgv;
            st.z = acc[ot][tj][2] + bgv;
            st.w = acc[ot][tj][3] + bgv;
            *(float4*)&out[((size_t)b * CH + o) * NPIX + j] = st;
        }
    }
}

// ---------------------------------------------------------------------------
extern "C" void kernel_launch(void* const* d_in, const int* in_sizes, int n_in,
                              void* d_out, int out_size, void* d_ws, size_t ws_size,
                              hipStream_t stream) {
    const float* x  = (const float*)d_in[0];
    const float* wq = (const float*)d_in[1];
    const float* bq = (const float*)d_in[2];
    const float* wk = (const float*)d_in[3];
    const float* bk = (const float*)d_in[4];
    const float* wv = (const float*)d_in[5];
    const float* bv = (const float*)d_in[6];
    const float* wg = (const float*)d_in[7];
    const float* bg = (const float*)d_in[8];
    float* out = (float*)d_out;

    unsigned short* W_all = (unsigned short*)d_ws;
    float* bias_all = (float*)(W_all + 384 * 256);
    unsigned short* qk = (unsigned short*)(bias_all + 384);
    unsigned short* vp = qk + (size_t)BATCH * NPIX * 128;

    prep_kernel<<<dim3(384), dim3(256), 0, stream>>>(wq, bq, wk, bk, wv, bv, wg, W_all, bias_all);
    qkvf_mfma<<<dim3(NPIX / 64, BATCH), dim3(256), 0, stream>>>(x, W_all, bias_all, qk, vp);
    attn_v11<<<dim3(NPIX / 64, BATCH), dim3(512), 0, stream>>>(qk, vp, bg, out);
}